// Round 1
// baseline (668.740 us; speedup 1.0000x reference)
//
#include <hip/hip_runtime.h>

#define NEGV (-1e30f)

namespace {
constexpr int B = 64;
constexpr int T = 2000;
constexpr int V = 256;
constexpr int S = 400;
constexpr int L = 2 * S + 1;     // 801 extended states
constexpr int NT = 832;          // 13 waves; one thread per state (+31 spare)
constexpr int CH = 13;           // rows per chunk: NT*4 floats = 3328 = CH*V
}

// One block per batch item. Alpha recursion over t in LDS double buffer,
// one barrier per step. Rows staged in LDS in CH-row chunks, prefetched
// into registers one chunk ahead (global->reg loads don't force vmcnt(0)
// at barriers, unlike global_load_lds).
__global__ __launch_bounds__(NT)
void ctc_alpha_kernel(const float* __restrict__ logp,
                      const int* __restrict__ targets,
                      const int* __restrict__ input_len,
                      const int* __restrict__ target_len,
                      float* __restrict__ ws)
{
  const int b   = blockIdx.x;
  const int tid = threadIdx.x;
  const float* lp = logp + (size_t)b * T * V;
  const int il = input_len[b];
  const int tl = target_len[b];
  const int Lb = 2 * tl + 1;

  __shared__ float rows[2][CH * V];   // 26.0 KB
  __shared__ float abuf[2][L + 2];    //  6.3 KB (2-elem NEG pad at front)

  // t-invariant per-thread constants
  const int  s = tid;
  const bool is_state = (s < L);
  int  e = 1;          // ext[s]: BLANK(=1) for even states
  bool skip = false;   // can_skip[s]
  if (is_state && (s & 1)) {
    const int* tg = targets + (size_t)b * S;
    const int k = s >> 1;
    e = tg[k];                              // targets >= 2, never blank
    skip = (k == 0) || (e != tg[k - 1]);
  }
  const bool valid = is_state && (s < Lb);

  // init both alpha buffers (incl. front pad) to NEG
  for (int i = tid; i < 2 * (L + 2); i += NT)
    (&abuf[0][0])[i] = NEGV;

  // load chunk 0 (rows t = 0..CH-1): exactly one float4 per thread
  {
    float4 r = *(const float4*)(lp + tid * 4);
    ((float4*)(&rows[0][0]))[tid] = r;
  }
  __syncthreads();

  // t = 0 init: alpha0[0] = logp[0][blank], alpha0[1] = logp[0][tgt[0]]
  float alpha = NEGV;
  if (s < 2) {
    alpha = rows[0][e];
    abuf[0][s + 2] = alpha;
  }
  __syncthreads();

  int cur = 0;
  const int NCH = (il + CH - 1) / CH;   // alpha frozen for t >= il: stop there
  for (int c = 0; c < NCH; ++c) {
    // prefetch chunk c+1 into registers (latency hidden behind CH steps)
    const long gbase = (long)(c + 1) * CH * V;
    const bool ok = (gbase + (long)(tid + 1) * 4 <= (long)T * V);
    float4 pre;
    if (ok) pre = *(const float4*)(lp + gbase + tid * 4);

    const float* rowc = &rows[c & 1][0];
    const int t0 = c * CH;
    const int iend = min(CH, il - t0);          // only t < il
    for (int i = (c == 0 ? 1 : 0); i < iend; ++i) {
      if (valid) {
        float a1  = abuf[cur][s + 1];           // alpha[s-1] (pad-shifted)
        float a2  = abuf[cur][s];               // alpha[s-2]
        float lpv = rowc[i * V + e];
        float a2m = skip ? a2 : NEGV;
        float m   = fmaxf(fmaxf(alpha, a1), a2m);
        float sum = __expf(alpha - m) + __expf(a1 - m) + __expf(a2m - m);
        alpha = m + __logf(sum) + lpv;
        abuf[cur ^ 1][s + 2] = alpha;
      }
      __syncthreads();
      cur ^= 1;
    }
    // commit prefetched chunk into the other row buffer
    if (ok) ((float4*)(&rows[(c & 1) ^ 1][0]))[tid] = pre;
    __syncthreads();
  }

  if (tid == 0) {
    const float ae  = abuf[cur][2 * tl + 2];
    const float ae1 = abuf[cur][2 * tl + 1];
    const float m   = fmaxf(ae, ae1);
    const float ll  = m + __logf(__expf(ae - m) + __expf(ae1 - m));
    float loss = -ll;
    if (!(loss < 1e29f)) loss = 0.0f;          // also catches NaN, like the ref
    ws[b] = loss / (float)tl;
  }
}

__global__ void ctc_reduce_kernel(const float* __restrict__ ws,
                                  float* __restrict__ out)
{
  float v = ws[threadIdx.x];
  #pragma unroll
  for (int o = 32; o > 0; o >>= 1)
    v += __shfl_down(v, o, 64);
  if (threadIdx.x == 0) out[0] = v * (1.0f / (float)B);
}

extern "C" void kernel_launch(void* const* d_in, const int* in_sizes, int n_in,
                              void* d_out, int out_size, void* d_ws, size_t ws_size,
                              hipStream_t stream) {
  const float* logp    = (const float*)d_in[0];
  const int*   targets = (const int*)d_in[1];
  const int*   il      = (const int*)d_in[2];
  const int*   tl      = (const int*)d_in[3];
  float* out = (float*)d_out;
  float* ws  = (float*)d_ws;   // 64 floats of scratch

  ctc_alpha_kernel<<<B, NT, 0, stream>>>(logp, targets, il, tl, ws);
  ctc_reduce_kernel<<<1, 64, 0, stream>>>(ws, out);
}